// Round 6
// baseline (3064.179 us; speedup 1.0000x reference)
//
#include <hip/hip_runtime.h>

// RegressiveAutoEncoder B=2048,T=512,F=8,H=128 — MFMA v6 (2 blocks/CU).
// 512 blocks x 512 threads, BT=4 batch rows/block, __launch_bounds__(512,4)
// -> 4 waves/SIMD from 2 independent blocks: barriers interleave.
// Single MFMA pass (20/wave/step): h AND U as rtn-bf16. x/y full precision
// (hi+lo k-slots vs rtn-W); bias via constant-1.0 k-slot (slot 16).
// A rows 0..3 real, 4..15 zero (reads exec-masked to n<4 -> 1/4 LDS BW).
// Redistribution: lane(q,n) gets C row q from lane(0,n): shfl_xor 16/32/48
// + 3 selects per gate; exactly 1 cell/lane. One barrier/step.

namespace {

typedef __attribute__((ext_vector_type(8))) short bf16x8;
typedef __attribute__((ext_vector_type(4))) float f32x4;

constexpr int T = 512, F = 8, H = 128, G4 = 512, NTH = 512, BT = 4;
constexpr int HS = 136;  // shorts per hb row (272B) -> rows land on bank offsets {0,4,8,12}
constexpr int XS = 32;   // shorts per xp row: [xhi 0..7 | xlo 8..15 | 1.0 @16 | 0...]

struct __align__(16) Smem {
  unsigned short hb[2][BT][HS];  // h rtn-bf16, A-layout, dbuf by step parity
  unsigned short xp[2][BT][XS];  // input (x_t / y_{t-1}) hi|lo|bias-one, dbuf
};

__device__ __forceinline__ float rcpf(float v) { return __builtin_amdgcn_rcpf(v); }
__device__ __forceinline__ float sigm(float v) { return rcpf(1.0f + __expf(-v)); }
__device__ __forceinline__ float tanh_(float v) { return 1.0f - 2.0f * rcpf(__expf(2.0f * v) + 1.0f); }

__device__ __forceinline__ unsigned short bf_rtn(float v) {
  unsigned u = __float_as_uint(v);
  return (unsigned short)((u + 0x7FFFu + ((u >> 16) & 1u)) >> 16);
}
__device__ __forceinline__ void split_tr(float v, unsigned short& hi, unsigned short& lo) {
  unsigned u = __float_as_uint(v);
  hi = (unsigned short)(u >> 16);
  lo = bf_rtn(v - __uint_as_float(u & 0xFFFF0000u));
}

__global__ __launch_bounds__(NTH, 4)
void rae_v6(const float* __restrict__ x,
            const float* __restrict__ Wenc, const float* __restrict__ Uenc, const float* __restrict__ benc,
            const float* __restrict__ Wdec, const float* __restrict__ Udec, const float* __restrict__ bdec,
            const float* __restrict__ Wout, const float* __restrict__ boutg,
            float* __restrict__ out)
{
  __shared__ Smem s;
  const int tid = threadIdx.x, lane = tid & 63, w = tid >> 6;
  const int q = lane >> 4, n = lane & 15;
  const long gb = (long)blockIdx.x * BT;

  // ---- zero LDS, then stage x_0 and the bias-one slots (barrier between:
  // different threads own the zero-write vs the staging-write) ----
  for (int i = tid; i < 2 * BT * HS; i += NTH) (&s.hb[0][0][0])[i] = 0;
  for (int i = tid; i < 2 * BT * XS; i += NTH) (&s.xp[0][0][0])[i] = 0;
  __syncthreads();
  if (tid < 32) {  // r = tid>>3 (0..3), f = tid&7
    unsigned short hv, lv;
    split_tr(x[(gb + (tid >> 3)) * (long)(T * F) + (tid & 7)], hv, lv);
    s.xp[0][tid >> 3][tid & 7] = hv;
    s.xp[0][tid >> 3][(tid & 7) + 8] = lv;
  }
  if (tid < 8) s.xp[tid >> 2][tid & 3][16] = 0x3F80;  // bf16(1.0) bias slot, both parities
  const float boutr = boutg[n & 7];
  float cst = 0.0f;  // one cell per lane: (row q, col w*16+n)
  __syncthreads();

  bf16x8 A[5];
  {
    bf16x8 zz = {0, 0, 0, 0, 0, 0, 0, 0};
#pragma unroll
    for (int kt = 0; kt < 5; ++kt) A[kt] = zz;  // h_0 = 0; lanes n>=4 keep zeros forever
  }

  bf16x8 B1[5][4];
  bf16x8 Bw[4];

  for (int ph = 0; ph < 2; ++ph) {
    const float* U  = ph ? Udec : Uenc;
    const float* W  = ph ? Wdec : Wenc;
    const float* bi = ph ? bdec : benc;

    // ---- B preload: kt<4 = rtn(U); kt=4 k-slots: 0..7 W (x_hi), 8..15 W (x_lo),
    // 16 bias, rest 0 ----
#pragma unroll
    for (int kt = 0; kt < 5; ++kt)
#pragma unroll
      for (int g = 0; g < 4; ++g) {
        const int col = g * 128 + w * 16 + n;
        bf16x8 b1;
#pragma unroll
        for (int j = 0; j < 8; ++j) {
          unsigned short v = 0;
          if (kt < 4) {
            v = bf_rtn(U[(kt * 32 + q * 8 + j) * G4 + col]);
          } else {
            const int kk = q * 8 + j;
            if (kk < 16)      v = bf_rtn(W[(kk & 7) * G4 + col]);
            else if (kk == 16) v = bf_rtn(bi[col]);
          }
          b1[j] = (short)v;
        }
        B1[kt][g] = b1;
      }

    if (ph == 1) {
      // Wout frags: N-cols 0..7 = Wout_hi, 8..15 = Wout_lo (fold via shfl_xor 8)
#pragma unroll
      for (int kt = 0; kt < 4; ++kt) {
        bf16x8 bw;
#pragma unroll
        for (int j = 0; j < 8; ++j) {
          unsigned short hv, lv; split_tr(Wout[(kt * 32 + q * 8 + j) * F + (n & 7)], hv, lv);
          bw[j] = (short)((n < 8) ? hv : lv);
        }
        Bw[kt] = bw;
      }
      if (tid < 32) {  // y_{-1} = x[:,T-1,:] into parity slot 0
        unsigned short hv, lv;
        split_tr(x[(gb + (tid >> 3)) * (long)(T * F) + (T - 1) * F + (tid & 7)], hv, lv);
        s.xp[0][tid >> 3][tid & 7] = hv;
        s.xp[0][tid >> 3][(tid & 7) + 8] = lv;
      }
      __syncthreads();
    }

    for (int t = 0; t < T; ++t) {
      const int pcur = t & 1, pnxt = (t + 1) & 1;
      float xnext = 0.f;
      if (ph == 0 && tid < 32 && t + 1 < T)
        xnext = x[(gb + (tid >> 3)) * (long)(T * F) + (t + 1) * F + (tid & 7)];

      if (n < BT) A[4] = *(const bf16x8*)&s.xp[pcur][n][q * 8];  // masked: 1/4 BW

      f32x4 acc[4];
#pragma unroll
      for (int g = 0; g < 4; ++g) acc[g] = f32x4{0.f, 0.f, 0.f, 0.f};
#pragma unroll
      for (int kt = 0; kt < 5; ++kt)
#pragma unroll
        for (int g = 0; g < 4; ++g)
          acc[g] = __builtin_amdgcn_mfma_f32_16x16x32_bf16(A[kt], B1[kt][g], acc[g], 0, 0, 0);

      // ---- redistribute: lane (q,n) takes C row q from lane (0,n) ----
      float z[4];
#pragma unroll
      for (int g = 0; g < 4; ++g) {
        float s1 = __shfl_xor(acc[g][1], 16, 64);
        float s2 = __shfl_xor(acc[g][2], 32, 64);
        float s3 = __shfl_xor(acc[g][3], 48, 64);
        z[g] = (q == 0) ? acc[g][0] : (q == 1) ? s1 : (q == 2) ? s2 : s3;
      }
      // ---- cell update: 1 cell/lane (row q, col w*16+n) ----
      cst = sigm(z[1]) * cst + sigm(z[0]) * tanh_(z[2]);
      const float h = sigm(z[3]) * tanh_(cst);
      s.hb[pnxt][q][w * 16 + n] = bf_rtn(h);

      if (ph == 0 && tid < 32 && t + 1 < T) {
        unsigned short hv, lv; split_tr(xnext, hv, lv);
        s.xp[pnxt][tid >> 3][tid & 7] = hv;
        s.xp[pnxt][tid >> 3][(tid & 7) + 8] = lv;
      }
      __syncthreads();  // the only barrier per step

      // h fragments for next iter / dense (masked to valid rows)
      if (n < BT) {
#pragma unroll
        for (int kt = 0; kt < 4; ++kt)
          A[kt] = *(const bf16x8*)&s.hb[pnxt][n][kt * 32 + q * 8];
      }

      if (ph == 1) {
        // dense y = relu(h@Wout + b), redundant per wave (4 MFMAs)
        f32x4 ay = {0.f, 0.f, 0.f, 0.f};
#pragma unroll
        for (int kt = 0; kt < 4; ++kt)
          ay = __builtin_amdgcn_mfma_f32_16x16x32_bf16(A[kt], Bw[kt], ay, 0, 0, 0);
        float y[4];
#pragma unroll
        for (int p = 0; p < 4; ++p)
          y[p] = fmaxf(ay[p] + __shfl_xor(ay[p], 8, 64) + boutr, 0.f);
        if (q == 0 && n < 8) {                 // rows p=0..3, col f=n
          if (w == 0) {
#pragma unroll
            for (int p = 0; p < 4; ++p)
              out[((gb + p) * T + t) * F + n] = y[p];
          }
#pragma unroll
          for (int p = 0; p < 4; ++p) {        // idempotent feedback (full precision)
            unsigned short hv, lv; split_tr(y[p], hv, lv);
            s.xp[pnxt][p][n]     = hv;
            s.xp[pnxt][p][n + 8] = lv;
          }
        }
      }
    }
  }
}

} // namespace

extern "C" void kernel_launch(void* const* d_in, const int* in_sizes, int n_in,
                              void* d_out, int out_size, void* d_ws, size_t ws_size,
                              hipStream_t stream) {
  const float* x    = (const float*)d_in[0];
  const float* Wenc = (const float*)d_in[1];
  const float* Uenc = (const float*)d_in[2];
  const float* benc = (const float*)d_in[3];
  const float* Wdec = (const float*)d_in[4];
  const float* Udec = (const float*)d_in[5];
  const float* bdec = (const float*)d_in[6];
  const float* Wout = (const float*)d_in[7];
  const float* bout = (const float*)d_in[8];
  float* out = (float*)d_out;

  const int Bsz = in_sizes[0] / (T * F);  // 2048
  const int nblocks = Bsz / BT;           // 512 -> 2 blocks/CU
  rae_v6<<<dim3(nblocks), dim3(NTH), 0, stream>>>(
      x, Wenc, Uenc, benc, Wdec, Udec, bdec, Wout, bout, out);
}

// Round 7
// 1906.663 us; speedup vs baseline: 1.6071x; 1.6071x over previous
//
#include <hip/hip_runtime.h>

// RegressiveAutoEncoder B=2048,T=512,F=8,H=128 — MFMA v7 (dual-group ILP).
// 256 blocks x 512 threads; block owns 8 batch rows as TWO independent
// 4-row groups (rows 0..3, 4..7), each in its own M=16 MFMA tile, sharing the
// register-resident B fragments. Two independent dependency chains per wave
// fill each other's latency stalls (LDS round-trips, shfl, exp chains) --
// occupancy is capped at 2 waves/SIMD by the 80-VGPR B1 set (R6 lesson:
// forcing 4 waves/EU spills and FETCH explodes 10x).
// Precision (validated v6): U,h = rtn-bf16 single pass; x/y hi+lo k-slots
// 128..143 vs rtn-W; bias via constant-1.0 k-slot 16. One barrier/step.
// Redistribute: lane(q,n) takes C row q from lane(0,n): shfl_xor 16/32/48.

namespace {

typedef __attribute__((ext_vector_type(8))) short bf16x8;
typedef __attribute__((ext_vector_type(4))) float f32x4;

constexpr int T = 512, F = 8, H = 128, G4 = 512, NTH = 512;
constexpr int HS = 136;  // shorts per hb row (272B, b128-aligned)
constexpr int XS = 32;   // shorts per xp row: [xhi 0..7 | xlo 8..15 | 1.0 @16 | 0]

struct __align__(16) Smem {
  unsigned short hb[2][8][HS];  // h rtn-bf16, rows 0..7 (group = r>>2), dbuf by parity
  unsigned short xp[2][8][XS];  // input (x_t / y_{t-1}) hi|lo|bias-one, dbuf
};

__device__ __forceinline__ float rcpf(float v) { return __builtin_amdgcn_rcpf(v); }
__device__ __forceinline__ float sigm(float v) { return rcpf(1.0f + __expf(-v)); }
__device__ __forceinline__ float tanh_(float v) { return 1.0f - 2.0f * rcpf(__expf(2.0f * v) + 1.0f); }

__device__ __forceinline__ unsigned short bf_rtn(float v) {
  unsigned u = __float_as_uint(v);
  return (unsigned short)((u + 0x7FFFu + ((u >> 16) & 1u)) >> 16);
}
__device__ __forceinline__ void split_tr(float v, unsigned short& hi, unsigned short& lo) {
  unsigned u = __float_as_uint(v);
  hi = (unsigned short)(u >> 16);
  lo = bf_rtn(v - __uint_as_float(u & 0xFFFF0000u));
}

__global__ __launch_bounds__(NTH, 2)
void rae_v7(const float* __restrict__ x,
            const float* __restrict__ Wenc, const float* __restrict__ Uenc, const float* __restrict__ benc,
            const float* __restrict__ Wdec, const float* __restrict__ Udec, const float* __restrict__ bdec,
            const float* __restrict__ Wout, const float* __restrict__ boutg,
            float* __restrict__ out)
{
  __shared__ Smem s;
  const int tid = threadIdx.x, lane = tid & 63, w = tid >> 6;
  const int q = lane >> 4, n = lane & 15;
  const long gb = (long)blockIdx.x * 8;

  for (int i = tid; i < 2 * 8 * HS; i += NTH) (&s.hb[0][0][0])[i] = 0;
  for (int i = tid; i < 2 * 8 * XS; i += NTH) (&s.xp[0][0][0])[i] = 0;
  __syncthreads();
  if (tid < 64) {  // stage x_0: r = tid>>3 (0..7), f = tid&7
    unsigned short hv, lv;
    split_tr(x[(gb + (tid >> 3)) * (long)(T * F) + (tid & 7)], hv, lv);
    s.xp[0][tid >> 3][tid & 7] = hv;
    s.xp[0][tid >> 3][(tid & 7) + 8] = lv;
  }
  if (tid < 16) s.xp[tid >> 3][tid & 7][16] = 0x3F80;  // bf16(1.0) bias slot
  const float boutr = boutg[n & 7];
  float cst[2] = {0.f, 0.f};  // one cell per lane per group: (row G*4+q, col w*16+n)
  __syncthreads();

  bf16x8 A[2][5];
  {
    bf16x8 zz = {0, 0, 0, 0, 0, 0, 0, 0};
#pragma unroll
    for (int G = 0; G < 2; ++G)
#pragma unroll
      for (int kt = 0; kt < 5; ++kt) A[G][kt] = zz;  // h_0 = 0; lanes n>=4 stay zero
  }

  bf16x8 B1[5][4];
  bf16x8 Bw[4];

  for (int ph = 0; ph < 2; ++ph) {
    const float* U  = ph ? Udec : Uenc;
    const float* W  = ph ? Wdec : Wenc;
    const float* bi = ph ? bdec : benc;

    // ---- B preload: kt<4 = rtn(U); kt=4 k-slots: 0..7 W(x_hi), 8..15 W(x_lo),
    // 16 = bias, rest 0 ----
#pragma unroll
    for (int kt = 0; kt < 5; ++kt)
#pragma unroll
      for (int g = 0; g < 4; ++g) {
        const int col = g * 128 + w * 16 + n;
        bf16x8 b1;
#pragma unroll
        for (int j = 0; j < 8; ++j) {
          unsigned short v = 0;
          if (kt < 4) {
            v = bf_rtn(U[(kt * 32 + q * 8 + j) * G4 + col]);
          } else {
            const int kk = q * 8 + j;
            if (kk < 16)       v = bf_rtn(W[(kk & 7) * G4 + col]);
            else if (kk == 16) v = bf_rtn(bi[col]);
          }
          b1[j] = (short)v;
        }
        B1[kt][g] = b1;
      }

    if (ph == 1) {
      // Wout frags: N-cols 0..7 = Wout_hi, 8..15 = Wout_lo (fold via shfl_xor 8)
#pragma unroll
      for (int kt = 0; kt < 4; ++kt) {
        bf16x8 bw;
#pragma unroll
        for (int j = 0; j < 8; ++j) {
          unsigned short hv, lv; split_tr(Wout[(kt * 32 + q * 8 + j) * F + (n & 7)], hv, lv);
          bw[j] = (short)((n < 8) ? hv : lv);
        }
        Bw[kt] = bw;
      }
      if (tid < 64) {  // y_{-1} = x[:,T-1,:] into parity slot 0
        unsigned short hv, lv;
        split_tr(x[(gb + (tid >> 3)) * (long)(T * F) + (T - 1) * F + (tid & 7)], hv, lv);
        s.xp[0][tid >> 3][tid & 7] = hv;
        s.xp[0][tid >> 3][(tid & 7) + 8] = lv;
      }
      __syncthreads();
    }

    for (int t = 0; t < T; ++t) {
      const int pcur = t & 1, pnxt = (t + 1) & 1;
      float xnext = 0.f;
      if (ph == 0 && tid < 64 && t + 1 < T)
        xnext = x[(gb + (tid >> 3)) * (long)(T * F) + (t + 1) * F + (tid & 7)];

      if (n < 4) {
#pragma unroll
        for (int G = 0; G < 2; ++G)
          A[G][4] = *(const bf16x8*)&s.xp[pcur][G * 4 + n][q * 8];
      }

      // ---- MFMA: 2 groups x 5 ksteps x 4 gates, 8 independent chains ----
      f32x4 acc[2][4];
#pragma unroll
      for (int G = 0; G < 2; ++G)
#pragma unroll
        for (int g = 0; g < 4; ++g) acc[G][g] = f32x4{0.f, 0.f, 0.f, 0.f};
#pragma unroll
      for (int kt = 0; kt < 5; ++kt)
#pragma unroll
        for (int g = 0; g < 4; ++g) {
          acc[0][g] = __builtin_amdgcn_mfma_f32_16x16x32_bf16(A[0][kt], B1[kt][g], acc[0][g], 0, 0, 0);
          acc[1][g] = __builtin_amdgcn_mfma_f32_16x16x32_bf16(A[1][kt], B1[kt][g], acc[1][g], 0, 0, 0);
        }

      // ---- redistribute + cell update, independently per group ----
#pragma unroll
      for (int G = 0; G < 2; ++G) {
        float z[4];
#pragma unroll
        for (int g = 0; g < 4; ++g) {
          float s1 = __shfl_xor(acc[G][g][1], 16, 64);
          float s2 = __shfl_xor(acc[G][g][2], 32, 64);
          float s3 = __shfl_xor(acc[G][g][3], 48, 64);
          z[g] = (q == 0) ? acc[G][g][0] : (q == 1) ? s1 : (q == 2) ? s2 : s3;
        }
        cst[G] = sigm(z[1]) * cst[G] + sigm(z[0]) * tanh_(z[2]);
        const float h = sigm(z[3]) * tanh_(cst[G]);
        s.hb[pnxt][G * 4 + q][w * 16 + n] = bf_rtn(h);
      }

      if (ph == 0 && tid < 64 && t + 1 < T) {
        unsigned short hv, lv; split_tr(xnext, hv, lv);
        s.xp[pnxt][tid >> 3][tid & 7] = hv;
        s.xp[pnxt][tid >> 3][(tid & 7) + 8] = lv;
      }
      __syncthreads();  // the only barrier per step

      // h fragments for next iter / dense
      if (n < 4) {
#pragma unroll
        for (int G = 0; G < 2; ++G)
#pragma unroll
          for (int kt = 0; kt < 4; ++kt)
            A[G][kt] = *(const bf16x8*)&s.hb[pnxt][G * 4 + n][kt * 32 + q * 8];
      }

      if (ph == 1) {
        // dense y = relu(h@Wout + b), redundant per wave, per group
#pragma unroll
        for (int G = 0; G < 2; ++G) {
          f32x4 ay = {0.f, 0.f, 0.f, 0.f};
#pragma unroll
          for (int kt = 0; kt < 4; ++kt)
            ay = __builtin_amdgcn_mfma_f32_16x16x32_bf16(A[G][kt], Bw[kt], ay, 0, 0, 0);
          float y[4];
#pragma unroll
          for (int p = 0; p < 4; ++p)
            y[p] = fmaxf(ay[p] + __shfl_xor(ay[p], 8, 64) + boutr, 0.f);
          if (q == 0 && n < 8) {               // rows G*4+p, col f=n
            if (w == 0) {
#pragma unroll
              for (int p = 0; p < 4; ++p)
                out[((gb + G * 4 + p) * T + t) * F + n] = y[p];
            }
#pragma unroll
            for (int p = 0; p < 4; ++p) {      // idempotent full-precision feedback
              unsigned short hv, lv; split_tr(y[p], hv, lv);
              s.xp[pnxt][G * 4 + p][n]     = hv;
              s.xp[pnxt][G * 4 + p][n + 8] = lv;
            }
          }
        }
      }
    }
  }
}

} // namespace

extern "C" void kernel_launch(void* const* d_in, const int* in_sizes, int n_in,
                              void* d_out, int out_size, void* d_ws, size_t ws_size,
                              hipStream_t stream) {
  const float* x    = (const float*)d_in[0];
  const float* Wenc = (const float*)d_in[1];
  const float* Uenc = (const float*)d_in[2];
  const float* benc = (const float*)d_in[3];
  const float* Wdec = (const float*)d_in[4];
  const float* Udec = (const float*)d_in[5];
  const float* bdec = (const float*)d_in[6];
  const float* Wout = (const float*)d_in[7];
  const float* bout = (const float*)d_in[8];
  float* out = (float*)d_out;

  const int Bsz = in_sizes[0] / (T * F);  // 2048
  const int nblocks = Bsz / 8;            // 256
  rae_v7<<<dim3(nblocks), dim3(NTH), 0, stream>>>(
      x, Wenc, Uenc, benc, Wdec, Udec, bdec, Wout, bout, out);
}